// Round 14
// baseline (2181.389 us; speedup 1.0000x reference)
//
#include <hip/hip_runtime.h>
#include <hip/hip_bf16.h>
#include <math.h>

// B=256, T=128; text 768->256, audio 74->128, video 35->128
// z[b][t][512] = [audio(128) | video(128) | text(256)]  (bf16)
// xp buffers stored bf16 in LSTM-fragment layout (see gemm epilogue).

typedef __attribute__((ext_vector_type(8))) short short8;   // 8 bf16
typedef __attribute__((ext_vector_type(4))) float f32x4;

__device__ __forceinline__ float sigm(float x) { return 1.0f / (1.0f + __expf(-x)); }
__device__ __forceinline__ float tanh_(float x) {
    float ax = fabsf(x);
    float e  = __expf(-2.0f * ax);
    float t  = (1.0f - e) / (1.0f + e);
    return copysignf(t, x);
}
__device__ __forceinline__ ushort f2bf(float x) {
    __hip_bfloat16 h = __float2bfloat16(x);
    return *reinterpret_cast<ushort*>(&h);
}
__device__ __forceinline__ float bf2f(ushort u) { return __uint_as_float(((unsigned)u) << 16); }

#define BARRIER_LIGHT() \
    do { asm volatile("s_waitcnt lgkmcnt(0)" ::: "memory"); \
         __builtin_amdgcn_s_barrier(); \
         asm volatile("" ::: "memory"); } while (0)

// ---------------------------------------------------------------------------
// Fused fp32 -> bf16 bulk convert for all 6 buffers (counts divisible by 8).
// Segment prefix: t 3145728 | a 303104 | v 143360 | wt 98304 | wa 4736 | wv 2240
// Total 3697472 groups -> grid 14444 blocks of 256 (R13 fix: was 14443,
// leaving the last 64 groups of W_ih_v unconverted = 0xAA poison).
// ---------------------------------------------------------------------------
__global__ void cvt_all(const float* __restrict__ t, const float* __restrict__ a,
                        const float* __restrict__ v, const float* __restrict__ wt,
                        const float* __restrict__ wa, const float* __restrict__ wv,
                        ushort* __restrict__ td, ushort* __restrict__ ad,
                        ushort* __restrict__ vd, ushort* __restrict__ wtd,
                        ushort* __restrict__ wad, ushort* __restrict__ wvd)
{
    int i = blockIdx.x * 256 + threadIdx.x;
    const float* s; ushort* d; int off;
    if (i < 3145728)      { s = t;  d = td;  off = i; }
    else if (i < 3448832) { s = a;  d = ad;  off = i - 3145728; }
    else if (i < 3592192) { s = v;  d = vd;  off = i - 3448832; }
    else if (i < 3690496) { s = wt; d = wtd; off = i - 3592192; }
    else if (i < 3695232) { s = wa; d = wad; off = i - 3690496; }
    else if (i < 3697472) { s = wv; d = wvd; off = i - 3695232; }
    else return;
    float4 A = ((const float4*)s)[2 * off];
    float4 B = ((const float4*)s)[2 * off + 1];
    short8 o;
    o[0] = f2bf(A.x); o[1] = f2bf(A.y); o[2] = f2bf(A.z); o[3] = f2bf(A.w);
    o[4] = f2bf(B.x); o[5] = f2bf(B.y); o[6] = f2bf(B.z); o[7] = f2bf(B.w);
    ((short8*)d)[off] = o;
}

// ---------------------------------------------------------------------------
// MFMA GEMM, bf16 inputs (R12-verified): gates = A*W^T + bias -> bf16
// fragment layouts:
//  text (N==1024): idx = ((((b>>4)*128+t)*8 + w)*8 + (g*2+s))*256 + (b&15)*16 + pl
//  a/v  (N==512):  idx = ((((b>>4)*128+t)*8 + w)*4 + g)*256 + (b&15)*16 + pl
// ---------------------------------------------------------------------------
__global__ __launch_bounds__(256) void gemm_mfma_b(
    const ushort* __restrict__ A, const ushort* __restrict__ W,
    const float* __restrict__ bias, ushort* __restrict__ C,
    int M, int N, int K)
{
    constexpr int STR = 40;
    __shared__ ushort As[128 * STR];
    __shared__ ushort Ws[128 * STR];

    const int tid  = threadIdx.x;
    const int lane = tid & 63;
    const int wave = tid >> 6;
    const int bm   = blockIdx.y * 128;
    const int bn   = blockIdx.x * 128;
    const int m0   = (wave >> 1) * 64;
    const int n0   = (wave & 1) * 64;
    const int row  = tid >> 1;
    const int kseg = (tid & 1) * 16;
    const int fr   = lane & 15;
    const int fk   = (lane >> 4) * 8;

    f32x4 acc[4][4];
#pragma unroll
    for (int i = 0; i < 4; ++i)
#pragma unroll
        for (int j = 0; j < 4; ++j) acc[i][j] = (f32x4)(0.f);

    const bool kvec = (K & 7) == 0;

    for (int k0 = 0; k0 < K; k0 += 32) {
        {
            const ushort* ap = A + (size_t)(bm + row) * K + k0 + kseg;
            if (kvec && (k0 + kseg + 16) <= K) {
                *(int4*)&As[row * STR + kseg]     = *(const int4*)ap;
                *(int4*)&As[row * STR + kseg + 8] = *(const int4*)(ap + 8);
            } else {
#pragma unroll
                for (int j = 0; j < 16; ++j) {
                    int kk = k0 + kseg + j;
                    As[row * STR + kseg + j] = (kk < K) ? ap[j] : (ushort)0;
                }
            }
        }
        {
            const ushort* wp = W + (size_t)(bn + row) * K + k0 + kseg;
            if (kvec && (k0 + kseg + 16) <= K) {
                *(int4*)&Ws[row * STR + kseg]     = *(const int4*)wp;
                *(int4*)&Ws[row * STR + kseg + 8] = *(const int4*)(wp + 8);
            } else {
#pragma unroll
                for (int j = 0; j < 16; ++j) {
                    int kk = k0 + kseg + j;
                    Ws[row * STR + kseg + j] = (kk < K) ? wp[j] : (ushort)0;
                }
            }
        }
        __syncthreads();

        short8 af[4], wf[4];
#pragma unroll
        for (int mi = 0; mi < 4; ++mi)
            af[mi] = *(const short8*)&As[(m0 + mi * 16 + fr) * STR + fk];
#pragma unroll
        for (int ni = 0; ni < 4; ++ni)
            wf[ni] = *(const short8*)&Ws[(n0 + ni * 16 + fr) * STR + fk];
#pragma unroll
        for (int mi = 0; mi < 4; ++mi)
#pragma unroll
            for (int ni = 0; ni < 4; ++ni)
                acc[mi][ni] = __builtin_amdgcn_mfma_f32_16x16x32_bf16(
                    af[mi], wf[ni], acc[mi][ni], 0, 0, 0);
        __syncthreads();
    }

#pragma unroll
    for (int ni = 0; ni < 4; ++ni) {
        const int col = bn + n0 + ni * 16 + fr;
        const float bb = bias[col];
#pragma unroll
        for (int mi = 0; mi < 4; ++mi)
#pragma unroll
            for (int q = 0; q < 4; ++q) {
                int r  = bm + m0 + mi * 16 + (lane >> 4) * 4 + q;
                int b  = r >> 7, t = r & 127;
                size_t idx;
                if (N == 1024) {
                    int g = col >> 8, w = (col >> 5) & 7, s = (col >> 4) & 1, pl = col & 15;
                    idx = ((((size_t)(b >> 4) * 128 + t) * 8 + w) * 8 + (g * 2 + s)) * 256
                        + (size_t)(b & 15) * 16 + pl;
                } else {
                    int g = col >> 7, wq = (col >> 4) & 7, pl = col & 15;
                    idx = ((((size_t)(b >> 4) * 128 + t) * 8 + wq) * 4 + g) * 256
                        + (size_t)(b & 15) * 16 + pl;
                }
                C[idx] = f2bf(acc[mi][ni][q] + bb);
            }
    }
}

// ---------------------------------------------------------------------------
// Pack W_hh into bf16 fragment-major layout (R12-verified bytes).
// TEXT: element (ti,k8,n,jj) at ti*512 + k8*128 + n*8 + jj, ti=(kt*8+w)*8+(g*2+s).
//   Per-lane (np,k8) direct load: WFt + ti*512 + k8*128 + np*8 (16B contiguous,
//   fully coalesced across lanes).
// A/V: fragment-major for per-lane VGPR loads.
// ---------------------------------------------------------------------------
__global__ void wfrag_pack(const float* __restrict__ Wt, const float* __restrict__ Wa,
                           const float* __restrict__ Wv, ushort* __restrict__ WFt,
                           ushort* __restrict__ WFa, ushort* __restrict__ WFv)
{
    int idx = blockIdx.x * 256 + threadIdx.x;
    if (idx < 262144) {
        int e = idx;
        int jj = e & 7, n = (e >> 3) & 15, k8 = (e >> 7) & 3;
        int ti = e >> 9;
        int gs = ti & 7, w = (ti >> 3) & 7, kt = ti >> 6;
        int g = gs >> 1, s = gs & 1;
        WFt[e] = f2bf(Wt[(size_t)(g * 256 + w * 32 + s * 16 + n) * 256 + kt * 32 + k8 * 8 + jj]);
    } else if (idx < 327680) {
        int e = idx - 262144;
        int jj = e & 7, k8 = (e >> 3) & 3, n = (e >> 5) & 15;
        int g = (e >> 9) & 3, w = (e >> 11) & 7, kt = (e >> 14) & 3;
        WFa[e] = f2bf(Wa[(size_t)(g * 128 + w * 16 + n) * 128 + kt * 32 + k8 * 8 + jj]);
    } else if (idx < 393216) {
        int e = idx - 327680;
        int jj = e & 7, k8 = (e >> 3) & 3, n = (e >> 5) & 15;
        int g = (e >> 9) & 3, w = (e >> 11) & 7, kt = (e >> 14) & 3;
        WFv[e] = f2bf(Wv[(size_t)(g * 128 + w * 16 + n) * 128 + kt * 32 + k8 * 8 + jj]);
    }
}

// ---------------------------------------------------------------------------
// Pack W1 / W2 to bf16 for the MFMA fusion head.
// ---------------------------------------------------------------------------
__global__ void wf_pack(const float* __restrict__ W1, const float* __restrict__ W2,
                        ushort* __restrict__ W1b, ushort* __restrict__ W2ab,
                        ushort* __restrict__ W2bb)
{
    int idx = blockIdx.x * 256 + threadIdx.x;
    if (idx >= 1048576) return;
    int r = idx >> 9, c = idx & 511;
    W1b[idx]  = f2bf(W1[idx]);
    W2ab[idx] = f2bf(W2[(size_t)r * 1025 + 1 + c]);
    W2bb[idx] = f2bf(W2[(size_t)r * 1025 + 513 + c]);
}

// ---------------------------------------------------------------------------
// MFMA LSTM recurrence v7: text W streamed L2 -> VGPR DIRECTLY (no LDS round
// trip: v5 pushed 1MB/step through the LDS port = the measured bottleneck).
// Single wt[8] buffer (32 regs) + per-kt sched_barrier(0) to cap hoisting ->
// ~110 VGPRs, no spill. Compiler emits counted vmcnt/lgkm (no gl_lds left).
// h in LDS double-buffer (16KB); one light barrier per step. A/V unchanged.
// ---------------------------------------------------------------------------
#define TEXT_STEP(T, XC, XN, RP)                                                   \
    do {                                                                           \
        f32x4 acc[8];                                                              \
        _Pragma("unroll") for (int e = 0; e < 8; ++e) acc[e] = (f32x4)(0.f);       \
        _Pragma("unroll") for (int kt = 0; kt < 8; ++kt) {                         \
            __builtin_amdgcn_sched_barrier(0);                                     \
            short8 wt[8];                                                          \
            _Pragma("unroll") for (int e = 0; e < 8; ++e)                          \
                wt[e] = *(const short8*)(wthr + (size_t)(kt * 64 + e) * 512);      \
            short8 hfk;                                                            \
            { int byt = (RP) * 8192 + np * 512 + kt * 64 + k8 * 16;                \
              hfk = *(const short8*)(hbase + (byt ^ ((np & 7) << 4))); }           \
            _Pragma("unroll") for (int e = 0; e < 8; ++e)                          \
                acc[e] = __builtin_amdgcn_mfma_f32_16x16x32_bf16(wt[e], hfk, acc[e], 0, 0, 0); \
        }                                                                          \
        __builtin_amdgcn_sched_barrier(0);                                         \
        _Pragma("unroll") for (int e = 0; e < 8; ++e) {                            \
            acc[e][0] += bf2f((ushort)((XC)[e].x & 0xffffu));                      \
            acc[e][1] += bf2f((ushort)((XC)[e].x >> 16));                          \
            acc[e][2] += bf2f((ushort)((XC)[e].y & 0xffffu));                      \
            acc[e][3] += bf2f((ushort)((XC)[e].y >> 16));                          \
        }                                                                          \
        uint2 hw[2];                                                               \
        _Pragma("unroll") for (int s = 0; s < 2; ++s) {                            \
            ushort hq[4];                                                          \
            _Pragma("unroll") for (int q = 0; q < 4; ++q) {                        \
                float iv = acc[0 + s][q], fv = acc[2 + s][q];                      \
                float gv = acc[4 + s][q], ov = acc[6 + s][q];                      \
                float cc = sigm(fv) * c_st[s][q] + sigm(iv) * tanh_(gv);           \
                c_st[s][q] = cc;                                                   \
                hq[q] = f2bf(sigm(ov) * tanh_(cc));                                \
            }                                                                      \
            hw[s].x = (uint)hq[0] | ((uint)hq[1] << 16);                           \
            hw[s].y = (uint)hq[2] | ((uint)hq[3] << 16);                           \
        }                                                                          \
        _Pragma("unroll") for (int s = 0; s < 2; ++s) {                            \
            int byt = ((RP) ^ 1) * 8192 + np * 512 + w * 64 + s * 32 + k8 * 8;     \
            *(uint2*)(hbase + (byt ^ ((np & 7) << 4))) = hw[s];                    \
            *(uint2*)(zb + zrow + (size_t)(T) * 512 + s * 16) = hw[s];             \
        }                                                                          \
        { const ushort* xrn = xbase + (size_t)(((T) + 1) & 127) * 16384;           \
          _Pragma("unroll") for (int e = 0; e < 8; ++e)                            \
              (XN)[e] = *(const uint2*)(xrn + e * 256); }                          \
        BARRIER_LIGHT();                                                           \
    } while (0)

#define AV_STEP(T, XC, XN, RP)                                                     \
    do {                                                                           \
        short8 hf[4];                                                              \
        _Pragma("unroll") for (int kt = 0; kt < 4; ++kt) {                         \
            int byt = (RP) * 4096 + np * 256 + kt * 64 + k8 * 16;                  \
            hf[kt] = *(const short8*)(hbase + (byt ^ ((np & 7) << 4)));            \
        }                                                                          \
        f32x4 acc[4];                                                              \
        _Pragma("unroll") for (int g = 0; g < 4; ++g) acc[g] = (f32x4)(0.f);       \
        _Pragma("unroll") for (int kt = 0; kt < 4; ++kt)                           \
            _Pragma("unroll") for (int g = 0; g < 4; ++g)                          \
                acc[g] = __builtin_amdgcn_mfma_f32_16x16x32_bf16(wres[kt][g], hf[kt], acc[g], 0, 0, 0); \
        { const ushort* xrn = xbase + (size_t)(((T) + 1) & 127) * 8192;            \
          _Pragma("unroll") for (int g = 0; g < 4; ++g)                            \
              (XN)[g] = *(const uint2*)(xrn + g * 256); }                          \
        _Pragma("unroll") for (int g = 0; g < 4; ++g) {                            \
            acc[g][0] += bf2f((ushort)((XC)[g].x & 0xffffu));                      \
            acc[g][1] += bf2f((ushort)((XC)[g].x >> 16));                          \
            acc[g][2] += bf2f((ushort)((XC)[g].y & 0xffffu));                      \
            acc[g][3] += bf2f((ushort)((XC)[g].y >> 16));                          \
        }                                                                          \
        ushort hq[4];                                                              \
        _Pragma("unroll") for (int q = 0; q < 4; ++q) {                            \
            float cc = sigm(acc[1][q]) * c_st0[q] + sigm(acc[0][q]) * tanh_(acc[2][q]); \
            c_st0[q] = cc;                                                         \
            hq[q] = f2bf(sigm(acc[3][q]) * tanh_(cc));                             \
        }                                                                          \
        uint2 hw;                                                                  \
        hw.x = (uint)hq[0] | ((uint)hq[1] << 16);                                  \
        hw.y = (uint)hq[2] | ((uint)hq[3] << 16);                                  \
        {                                                                          \
            int byt = ((RP) ^ 1) * 4096 + np * 256 + w * 32 + k8 * 8;              \
            *(uint2*)(hbase + (byt ^ ((np & 7) << 4))) = hw;                       \
            *(uint2*)(zb + zrow + (size_t)(T) * 512) = hw;                         \
        }                                                                          \
        BARRIER_LIGHT();                                                           \
    } while (0)

__global__ __launch_bounds__(512) void lstm_mfma7(
    const ushort* __restrict__ xpt, const ushort* __restrict__ xpa,
    const ushort* __restrict__ xpv, const ushort* __restrict__ WFt,
    const ushort* __restrict__ WFa, const ushort* __restrict__ WFv,
    ushort* __restrict__ zb)
{
    __shared__ __align__(16) char smem[16384];    // h double-buffer only
    const int tid  = threadIdx.x;
    const int lane = tid & 63;
    const int w    = tid >> 6;
    const int np   = lane & 15;      // batch column
    const int k8   = lane >> 4;      // k-chunk / row-quad
    const int bid  = blockIdx.x;
    char* hbase = smem;

    if (bid < 16) {
        // ------------------------- text: H=256, K=256 -------------------------
        const int bt = bid;
        const ushort* xbase = xpt + (size_t)bt * 2097152 + w * 2048 + np * 16 + k8 * 4;
        const ushort* wthr  = WFt + (size_t)(w * 8) * 512 + k8 * 128 + np * 8;
        const size_t  zrow  = ((size_t)(bt * 16 + np) * 128) * 512 + 256 + w * 32 + k8 * 4;

        uint2 xvA[8], xvB[8];
#pragma unroll
        for (int e = 0; e < 8; ++e) xvA[e] = *(const uint2*)(xbase + e * 256);

        for (int i = tid; i < 4096; i += 512) ((uint*)hbase)[i] = 0u;
        float c_st[2][4];
#pragma unroll
        for (int s = 0; s < 2; ++s)
#pragma unroll
            for (int q = 0; q < 4; ++q) c_st[s][q] = 0.f;
        __syncthreads();

#pragma unroll 1
        for (int t = 0; t < 128; t += 2) {
            TEXT_STEP(t,     xvA, xvB, 0);
            TEXT_STEP(t + 1, xvB, xvA, 1);
        }
    } else {
        // ----------------------- audio / video: H=128, K=128 -------------------
        const bool isA = bid < 32;
        const int bt = bid - (isA ? 16 : 32);
        const ushort* xp = isA ? xpa : xpv;
        const ushort* WF = isA ? WFa : WFv;
        const int zoff = isA ? 0 : 128;

        short8 wres[4][4];
#pragma unroll
        for (int kt = 0; kt < 4; ++kt)
#pragma unroll
            for (int g = 0; g < 4; ++g)
                wres[kt][g] = *(const short8*)(WF + (size_t)((kt * 8 + w) * 4 + g) * 512 + np * 32 + k8 * 8);
        for (int i = tid; i < 2048; i += 512) ((uint*)hbase)[i] = 0u;
        float c_st0[4];
#pragma unroll
        for (int q = 0; q < 4; ++q) c_st0[q] = 0.f;
        __syncthreads();

        const ushort* xbase = xp + (size_t)bt * 1048576 + w * 1024 + np * 16 + k8 * 4;
        const size_t  zrow  = ((size_t)(bt * 16 + np) * 128) * 512 + zoff + w * 16 + k8 * 4;

        uint2 xvA[4], xvB[4];
#pragma unroll
        for (int g = 0; g < 4; ++g) xvA[g] = *(const uint2*)(xbase + g * 256);

#pragma unroll 1
        for (int t = 0; t < 128; t += 2) {
            AV_STEP(t,     xvA, xvB, 0);
            AV_STEP(t + 1, xvB, xvA, 1);
        }
    }
}

// ---------------------------------------------------------------------------
// MFMA fusion head (verified R2-R12).
// ---------------------------------------------------------------------------
__global__ __launch_bounds__(256) void fuse_mfma(
    const ushort* __restrict__ zb, const ushort* __restrict__ W1b,
    const ushort* __restrict__ W2ab, const ushort* __restrict__ W2bb,
    const float* __restrict__ b1, const float* __restrict__ b2,
    const float* __restrict__ W2, float* __restrict__ zf)
{
    constexpr int STR = 40;
    __shared__ ushort As[64 * STR];
    __shared__ ushort W1s[256 * STR];
    __shared__ ushort W2s[256 * STR];

    const int tid  = threadIdx.x;
    const int lane = tid & 63;
    const int wave = tid >> 6;
    const int b    = blockIdx.y;
    const int r0   = blockIdx.x * 256;
    const int n0w  = wave * 64;

    const int a_row  = tid >> 2;
    const int a_c8   = (tid & 3) * 8;
    const int fr_row = lane & 15;
    const int fr_k   = (lane >> 4) * 8;

    f32x4 acc1[4][4], acc2[4][4];
#pragma unroll
    for (int i = 0; i < 4; ++i)
#pragma unroll
        for (int j = 0; j < 4; ++j) {
            acc1[i][j] = (f32x4)(0.f);
            acc2[i][j] = (f32x4)(0.f);
        }

    for (int pass = 0; pass < 2; ++pass) {
        const ushort* wsrc = pass ? W2bb : W2ab;
        for (int c0 = 0; c0 < 512; c0 += 32) {
            {
                const int4 v = *(const int4*)(zb +
                    (((size_t)b * 128 + 2 * a_row + pass) * 512 + c0 + a_c8));
                *(int4*)&As[a_row * STR + a_c8] = v;
            }
            if (pass == 0) {
                const ushort* w1p = W1b + (size_t)(r0 + tid) * 512 + c0;
#pragma unroll
                for (int j = 0; j < 4; ++j)
                    *(int4*)&W1s[tid * STR + j * 8] = *(const int4*)(w1p + j * 8);
            }
            {
                const ushort* w2p = wsrc + (size_t)(r0 + tid) * 512 + c0;
#pragma unroll
                for (int j = 0; j < 4; ++j)
                    *(int4*)&W2s[tid * STR + j * 8] = *(const int4*)(w2p + j * 8);
            }
            __syncthreads();

            short8 af[4], w2f[4];
#pragma unroll
            for (int mi = 0; mi < 4; ++mi)
                af[mi] = *(const short8*)&As[(mi * 16 + fr_row) * STR + fr_k];
#pragma unroll
            for (int ni = 0; ni < 4; ++ni)
                w2f[ni] = *(const short8*)&W2s[(n0w + ni * 16 + fr_row) * STR + fr_k];

            if (pass == 0) {
                short8 w1f[4];
#pragma unroll
                for (int ni = 0; ni < 4; ++ni)
                    w1f[ni] = *(const short8*)&W1s[(n0w + ni * 16 + fr_row) * STR + fr_k];
#pragma unroll
                for (int mi = 0; mi < 4; ++mi)
#pragma unroll
                    for (int ni = 0; ni < 4; ++ni) {
                        acc1[mi][ni] = __builtin_amdgcn_mfma_f32_16x16x32_bf16(
                            af[mi], w1f[ni], acc1[mi][ni], 0, 0, 0);
                        acc2[mi][ni] = __builtin_amdgcn_mfma_f32_16x16x32_bf16(
                            af[mi], w2f[ni], acc2[mi][ni], 0, 0, 0);
                    }
            } else {
#pragma unroll
                for (int mi = 0; mi < 4; ++mi)
#pragma unroll
                    for (int ni = 0; ni < 4; ++ni)
                        acc2[mi][ni] = __builtin_amdgcn_mfma_f32_16x16x32_bf16(
                            af[mi], w2f[ni], acc2[mi][ni], 0, 0, 0);
            }
            __syncthreads();
        }
    }

#pragma unroll
    for (int ni = 0; ni < 4; ++ni) {
        const int r = r0 + n0w + ni * 16 + fr_row;
        const float bb1 = b1[r];
        const float bb2 = b2[r] + W2[(size_t)r * 1025];
        float s = 0.f;
#pragma unroll
        for (int mi = 0; mi < 4; ++mi)
#pragma unroll
            for (int q = 0; q < 4; ++q)
                s += (acc1[mi][ni][q] + bb1) * (acc2[mi][ni][q] + bb2);
        s += __shfl_xor(s, 16);
        s += __shfl_xor(s, 32);
        if ((lane >> 4) == 0)
            zf[(size_t)b * 2048 + r] = s * (1.0f / 64.0f);
    }
}

__global__ void final_out(const float* __restrict__ zf, const float* __restrict__ fw,
                          float* __restrict__ out)
{
    int idx = blockIdx.x * 256 + threadIdx.x;
    int b = idx >> 4, o = idx & 15;
    float s = 0.f;
#pragma unroll
    for (int r = 0; r < 128; ++r)
        s = fmaf(fw[r], zf[(size_t)b * 2048 + r * 16 + o], s);
    out[idx] = s;
}

extern "C" void kernel_launch(void* const* d_in, const int* in_sizes, int n_in,
                              void* d_out, int out_size, void* d_ws, size_t ws_size,
                              hipStream_t stream)
{
    const float* text_x  = (const float*)d_in[0];
    const float* audio_x = (const float*)d_in[1];
    const float* video_x = (const float*)d_in[2];
    const float* W_ih_t  = (const float*)d_in[3];
    const float* W_hh_t  = (const float*)d_in[4];
    const float* b_t     = (const float*)d_in[5];
    const float* W_ih_a  = (const float*)d_in[6];
    const float* W_hh_a  = (const float*)d_in[7];
    const float* b_a     = (const float*)d_in[8];
    const float* W_ih_v  = (const float*)d_in[9];
    const float* W_hh_v  = (const float*)d_in[10];
    const float* b_v     = (const float*)d_in[11];
    const float* W1      = (const float*)d_in[12];
    const float* b1      = (const float*)d_in[13];
    const float* W2      = (const float*)d_in[14];
    const float* b2      = (const float*)d_in[15];
    const float* fw      = (const float*)d_in[16];
    float* out = (float*)d_out;

    // workspace layout (bytes)
    char* base = (char*)d_ws;
    ushort* xpt  = (ushort*)(base);                 // 67108864
    ushort* xpa  = (ushort*)(base + 67108864);      // 33554432
    ushort* xpv  = (ushort*)(base + 100663296);     // 33554432
    ushort* zbuf = (ushort*)(base + 134217728);     // 33554432
    ushort* WFt  = (ushort*)(base + 167772160);     //   524288
    ushort* WFa  = (ushort*)(base + 168296448);     //   131072
    ushort* WFv  = (ushort*)(base + 168427520);     //   131072
    ushort* W1b  = (ushort*)(base + 168558592);     //  2097152
    ushort* W2ab = (ushort*)(base + 170655744);     //  2097152
    ushort* W2bb = (ushort*)(base + 172752896);     //  2097152
    float*  zf   = (float*)(base + 174850048);      //  2097152
    ushort* txb  = (ushort*)(base + 176947200);     // 50331648
    ushort* axb  = (ushort*)(base + 227278848);     //  4849664
    ushort* vxb  = (ushort*)(base + 232128512);     //  2293760
    ushort* wtb  = (ushort*)(base + 234422272);     //  1572864
    ushort* wab  = (ushort*)(base + 235995136);     //    75776
    ushort* wvb  = (ushort*)(base + 236070912);     //    35840

    cvt_all<<<14444, 256, 0, stream>>>(text_x, audio_x, video_x, W_ih_t, W_ih_a, W_ih_v,
                                       txb, axb, vxb, wtb, wab, wvb);

    gemm_mfma_b<<<dim3(8, 256), 256, 0, stream>>>(txb, wtb, b_t, xpt, 32768, 1024, 768);
    gemm_mfma_b<<<dim3(4, 256), 256, 0, stream>>>(axb, wab, b_a, xpa, 32768, 512, 74);
    gemm_mfma_b<<<dim3(4, 256), 256, 0, stream>>>(vxb, wvb, b_v, xpv, 32768, 512, 35);
    wfrag_pack<<<1536, 256, 0, stream>>>(W_hh_t, W_hh_a, W_hh_v, WFt, WFa, WFv);
    wf_pack<<<4096, 256, 0, stream>>>(W1, W2, W1b, W2ab, W2bb);
    lstm_mfma7<<<48, 512, 0, stream>>>(xpt, xpa, xpv, WFt, WFa, WFv, zbuf);
    fuse_mfma<<<dim3(8, 256), 256, 0, stream>>>(zbuf, W1b, W2ab, W2bb, b1, b2, W2, zf);
    final_out<<<16, 256, 0, stream>>>(zf, fw, out);
}

// Round 15
// 1582.178 us; speedup vs baseline: 1.3787x; 1.3787x over previous
//
#include <hip/hip_runtime.h>
#include <hip/hip_bf16.h>
#include <math.h>

// B=256, T=128; text 768->256, audio 74->128, video 35->128
// z[b][t][512] = [audio(128) | video(128) | text(256)]  (bf16)
// xp buffers stored bf16 in LSTM-fragment layout (see gemm epilogue).

typedef __attribute__((ext_vector_type(8))) short short8;   // 8 bf16
typedef __attribute__((ext_vector_type(4))) float f32x4;

__device__ __forceinline__ float sigm(float x) { return 1.0f / (1.0f + __expf(-x)); }
__device__ __forceinline__ float tanh_(float x) {
    float ax = fabsf(x);
    float e  = __expf(-2.0f * ax);
    float t  = (1.0f - e) / (1.0f + e);
    return copysignf(t, x);
}
__device__ __forceinline__ ushort f2bf(float x) {
    __hip_bfloat16 h = __float2bfloat16(x);
    return *reinterpret_cast<ushort*>(&h);
}
__device__ __forceinline__ float bf2f(ushort u) { return __uint_as_float(((unsigned)u) << 16); }

__device__ __forceinline__ void gl_lds16(const void* g, void* l) {
    __builtin_amdgcn_global_load_lds(
        (const __attribute__((address_space(1))) unsigned int*)g,
        (__attribute__((address_space(3))) unsigned int*)l, 16, 0, 0);
}

#define BARRIER_LIGHT() \
    do { asm volatile("s_waitcnt lgkmcnt(0)" ::: "memory"); \
         __builtin_amdgcn_s_barrier(); \
         asm volatile("" ::: "memory"); } while (0)

// ---------------------------------------------------------------------------
// Fused fp32 -> bf16 bulk convert for all 6 buffers (counts divisible by 8).
// Segment prefix: t 3145728 | a 303104 | v 143360 | wt 98304 | wa 4736 | wv 2240
// Total 3697472 groups -> grid 14444 blocks of 256.
// ---------------------------------------------------------------------------
__global__ void cvt_all(const float* __restrict__ t, const float* __restrict__ a,
                        const float* __restrict__ v, const float* __restrict__ wt,
                        const float* __restrict__ wa, const float* __restrict__ wv,
                        ushort* __restrict__ td, ushort* __restrict__ ad,
                        ushort* __restrict__ vd, ushort* __restrict__ wtd,
                        ushort* __restrict__ wad, ushort* __restrict__ wvd)
{
    int i = blockIdx.x * 256 + threadIdx.x;
    const float* s; ushort* d; int off;
    if (i < 3145728)      { s = t;  d = td;  off = i; }
    else if (i < 3448832) { s = a;  d = ad;  off = i - 3145728; }
    else if (i < 3592192) { s = v;  d = vd;  off = i - 3448832; }
    else if (i < 3690496) { s = wt; d = wtd; off = i - 3592192; }
    else if (i < 3695232) { s = wa; d = wad; off = i - 3690496; }
    else if (i < 3697472) { s = wv; d = wvd; off = i - 3695232; }
    else return;
    float4 A = ((const float4*)s)[2 * off];
    float4 B = ((const float4*)s)[2 * off + 1];
    short8 o;
    o[0] = f2bf(A.x); o[1] = f2bf(A.y); o[2] = f2bf(A.z); o[3] = f2bf(A.w);
    o[4] = f2bf(B.x); o[5] = f2bf(B.y); o[6] = f2bf(B.z); o[7] = f2bf(B.w);
    ((short8*)d)[off] = o;
}

// ---------------------------------------------------------------------------
// MFMA GEMM, bf16 inputs (R12-verified): gates = A*W^T + bias -> bf16
// fragment layouts:
//  text (N==1024): idx = ((((b>>4)*128+t)*8 + w)*8 + (g*2+s))*256 + (b&15)*16 + pl
//  a/v  (N==512):  idx = ((((b>>4)*128+t)*8 + w)*4 + g)*256 + (b&15)*16 + pl
// ---------------------------------------------------------------------------
__global__ __launch_bounds__(256) void gemm_mfma_b(
    const ushort* __restrict__ A, const ushort* __restrict__ W,
    const float* __restrict__ bias, ushort* __restrict__ C,
    int M, int N, int K)
{
    constexpr int STR = 40;
    __shared__ ushort As[128 * STR];
    __shared__ ushort Ws[128 * STR];

    const int tid  = threadIdx.x;
    const int lane = tid & 63;
    const int wave = tid >> 6;
    const int bm   = blockIdx.y * 128;
    const int bn   = blockIdx.x * 128;
    const int m0   = (wave >> 1) * 64;
    const int n0   = (wave & 1) * 64;
    const int row  = tid >> 1;
    const int kseg = (tid & 1) * 16;
    const int fr   = lane & 15;
    const int fk   = (lane >> 4) * 8;

    f32x4 acc[4][4];
#pragma unroll
    for (int i = 0; i < 4; ++i)
#pragma unroll
        for (int j = 0; j < 4; ++j) acc[i][j] = (f32x4)(0.f);

    const bool kvec = (K & 7) == 0;

    for (int k0 = 0; k0 < K; k0 += 32) {
        {
            const ushort* ap = A + (size_t)(bm + row) * K + k0 + kseg;
            if (kvec && (k0 + kseg + 16) <= K) {
                *(int4*)&As[row * STR + kseg]     = *(const int4*)ap;
                *(int4*)&As[row * STR + kseg + 8] = *(const int4*)(ap + 8);
            } else {
#pragma unroll
                for (int j = 0; j < 16; ++j) {
                    int kk = k0 + kseg + j;
                    As[row * STR + kseg + j] = (kk < K) ? ap[j] : (ushort)0;
                }
            }
        }
        {
            const ushort* wp = W + (size_t)(bn + row) * K + k0 + kseg;
            if (kvec && (k0 + kseg + 16) <= K) {
                *(int4*)&Ws[row * STR + kseg]     = *(const int4*)wp;
                *(int4*)&Ws[row * STR + kseg + 8] = *(const int4*)(wp + 8);
            } else {
#pragma unroll
                for (int j = 0; j < 16; ++j) {
                    int kk = k0 + kseg + j;
                    Ws[row * STR + kseg + j] = (kk < K) ? wp[j] : (ushort)0;
                }
            }
        }
        __syncthreads();

        short8 af[4], wf[4];
#pragma unroll
        for (int mi = 0; mi < 4; ++mi)
            af[mi] = *(const short8*)&As[(m0 + mi * 16 + fr) * STR + fk];
#pragma unroll
        for (int ni = 0; ni < 4; ++ni)
            wf[ni] = *(const short8*)&Ws[(n0 + ni * 16 + fr) * STR + fk];
#pragma unroll
        for (int mi = 0; mi < 4; ++mi)
#pragma unroll
            for (int ni = 0; ni < 4; ++ni)
                acc[mi][ni] = __builtin_amdgcn_mfma_f32_16x16x32_bf16(
                    af[mi], wf[ni], acc[mi][ni], 0, 0, 0);
        __syncthreads();
    }

#pragma unroll
    for (int ni = 0; ni < 4; ++ni) {
        const int col = bn + n0 + ni * 16 + fr;
        const float bb = bias[col];
#pragma unroll
        for (int mi = 0; mi < 4; ++mi)
#pragma unroll
            for (int q = 0; q < 4; ++q) {
                int r  = bm + m0 + mi * 16 + (lane >> 4) * 4 + q;
                int b  = r >> 7, t = r & 127;
                size_t idx;
                if (N == 1024) {
                    int g = col >> 8, w = (col >> 5) & 7, s = (col >> 4) & 1, pl = col & 15;
                    idx = ((((size_t)(b >> 4) * 128 + t) * 8 + w) * 8 + (g * 2 + s)) * 256
                        + (size_t)(b & 15) * 16 + pl;
                } else {
                    int g = col >> 7, wq = (col >> 4) & 7, pl = col & 15;
                    idx = ((((size_t)(b >> 4) * 128 + t) * 8 + wq) * 4 + g) * 256
                        + (size_t)(b & 15) * 16 + pl;
                }
                C[idx] = f2bf(acc[mi][ni][q] + bb);
            }
    }
}

// ---------------------------------------------------------------------------
// Pack W_hh into bf16 fragment-major layout (R12-verified bytes).
// TEXT: element (ti,k8,n,jj) at ti*512 + k8*128 + n*8 + jj, ti=(kt*8+w)*8+(g*2+s)
//   (lane order: gl_lds16 linear dst + lane*16 ds_read both conflict-free).
// A/V: fragment-major for per-lane VGPR loads.
// ---------------------------------------------------------------------------
__global__ void wfrag_pack(const float* __restrict__ Wt, const float* __restrict__ Wa,
                           const float* __restrict__ Wv, ushort* __restrict__ WFt,
                           ushort* __restrict__ WFa, ushort* __restrict__ WFv)
{
    int idx = blockIdx.x * 256 + threadIdx.x;
    if (idx < 262144) {
        int e = idx;
        int jj = e & 7, n = (e >> 3) & 15, k8 = (e >> 7) & 3;
        int ti = e >> 9;
        int gs = ti & 7, w = (ti >> 3) & 7, kt = ti >> 6;
        int g = gs >> 1, s = gs & 1;
        WFt[e] = f2bf(Wt[(size_t)(g * 256 + w * 32 + s * 16 + n) * 256 + kt * 32 + k8 * 8 + jj]);
    } else if (idx < 327680) {
        int e = idx - 262144;
        int jj = e & 7, k8 = (e >> 3) & 3, n = (e >> 5) & 15;
        int g = (e >> 9) & 3, w = (e >> 11) & 7, kt = (e >> 14) & 3;
        WFa[e] = f2bf(Wa[(size_t)(g * 128 + w * 16 + n) * 128 + kt * 32 + k8 * 8 + jj]);
    } else if (idx < 393216) {
        int e = idx - 327680;
        int jj = e & 7, k8 = (e >> 3) & 3, n = (e >> 5) & 15;
        int g = (e >> 9) & 3, w = (e >> 11) & 7, kt = (e >> 14) & 3;
        WFv[e] = f2bf(Wv[(size_t)(g * 128 + w * 16 + n) * 128 + kt * 32 + k8 * 8 + jj]);
    }
}

// ---------------------------------------------------------------------------
// Pack W1 / W2 to bf16 for the MFMA fusion head.
// ---------------------------------------------------------------------------
__global__ void wf_pack(const float* __restrict__ W1, const float* __restrict__ W2,
                        ushort* __restrict__ W1b, ushort* __restrict__ W2ab,
                        ushort* __restrict__ W2bb)
{
    int idx = blockIdx.x * 256 + threadIdx.x;
    if (idx >= 1048576) return;
    int r = idx >> 9, c = idx & 511;
    W1b[idx]  = f2bf(W1[idx]);
    W2ab[idx] = f2bf(W2[(size_t)r * 1025 + 1 + c]);
    W2bb[idx] = f2bf(W2[(size_t)r * 1025 + 513 + c]);
}

// ---------------------------------------------------------------------------
// MFMA LSTM recurrence v5 (R12-verified, 985 us — the empirical optimum of
// {VGPR-resident (spills), multi-CU resident + global sync (sync cost),
//  direct L2->VGPR (spill + latency)}). Text W streamed via global_load_lds
// into per-wave LDS double-buffers with counted vmcnt waits; A/V W
// VGPR-resident; h LDS double-buffer; one light barrier per step.
// ---------------------------------------------------------------------------
#define STAGE_W(KT)                                                                \
    do {                                                                           \
        const char* gs_ = (const char*)WFt + (size_t)(((KT) * 8 + w) * 8) * 1024   \
                          + lane * 16;                                             \
        char* ld_ = wbuf + ((KT) & 1) * 8192;                                      \
        _Pragma("unroll") for (int e_ = 0; e_ < 8; ++e_)                           \
            gl_lds16(gs_ + e_ * 1024, ld_ + e_ * 1024);                            \
    } while (0)

#define TEXT_STEP(T, XC, XN, RP)                                                   \
    do {                                                                           \
        f32x4 acc[8];                                                              \
        _Pragma("unroll") for (int e = 0; e < 8; ++e) acc[e] = (f32x4)(0.f);       \
        _Pragma("unroll") for (int kt = 0; kt < 8; ++kt) {                         \
            if (kt < 2) { asm volatile("s_waitcnt vmcnt(16)" ::: "memory"); }      \
            else        { asm volatile("s_waitcnt vmcnt(8)" ::: "memory"); }       \
            __builtin_amdgcn_sched_barrier(0);                                     \
            short8 wt[8];                                                          \
            _Pragma("unroll") for (int e = 0; e < 8; ++e)                          \
                wt[e] = *(const short8*)(wbuf + (kt & 1) * 8192 + e * 1024 + lane * 16); \
            short8 hfk;                                                            \
            { int byt = (RP) * 8192 + np * 512 + kt * 64 + k8 * 16;                \
              hfk = *(const short8*)(hbase + (byt ^ ((np & 7) << 4))); }           \
            asm volatile("s_waitcnt lgkmcnt(0)" ::: "memory");                     \
            __builtin_amdgcn_sched_barrier(0);                                     \
            STAGE_W((kt + 2) & 7);                                                 \
            __builtin_amdgcn_sched_barrier(0);                                     \
            _Pragma("unroll") for (int e = 0; e < 8; ++e)                          \
                acc[e] = __builtin_amdgcn_mfma_f32_16x16x32_bf16(wt[e], hfk, acc[e], 0, 0, 0); \
        }                                                                          \
        _Pragma("unroll") for (int e = 0; e < 8; ++e) {                            \
            acc[e][0] += bf2f((ushort)((XC)[e].x & 0xffffu));                      \
            acc[e][1] += bf2f((ushort)((XC)[e].x >> 16));                          \
            acc[e][2] += bf2f((ushort)((XC)[e].y & 0xffffu));                      \
            acc[e][3] += bf2f((ushort)((XC)[e].y >> 16));                          \
        }                                                                          \
        uint2 hw[2];                                                               \
        _Pragma("unroll") for (int s = 0; s < 2; ++s) {                            \
            ushort hq[4];                                                          \
            _Pragma("unroll") for (int q = 0; q < 4; ++q) {                        \
                float iv = acc[0 + s][q], fv = acc[2 + s][q];                      \
                float gv = acc[4 + s][q], ov = acc[6 + s][q];                      \
                float cc = sigm(fv) * c_st[s][q] + sigm(iv) * tanh_(gv);           \
                c_st[s][q] = cc;                                                   \
                hq[q] = f2bf(sigm(ov) * tanh_(cc));                                \
            }                                                                      \
            hw[s].x = (uint)hq[0] | ((uint)hq[1] << 16);                           \
            hw[s].y = (uint)hq[2] | ((uint)hq[3] << 16);                           \
        }                                                                          \
        __builtin_amdgcn_sched_barrier(0);                                         \
        _Pragma("unroll") for (int s = 0; s < 2; ++s) {                            \
            int byt = ((RP) ^ 1) * 8192 + np * 512 + w * 64 + s * 32 + k8 * 8;     \
            *(uint2*)(hbase + (byt ^ ((np & 7) << 4))) = hw[s];                    \
            *(uint2*)(zb + zrow + (size_t)(T) * 512 + s * 16) = hw[s];             \
        }                                                                          \
        { const ushort* xrn = xbase + (size_t)(((T) + 1) & 127) * 16384;           \
          _Pragma("unroll") for (int e = 0; e < 8; ++e)                            \
              (XN)[e] = *(const uint2*)(xrn + e * 256); }                          \
        __builtin_amdgcn_sched_barrier(0);                                         \
        BARRIER_LIGHT();                                                           \
    } while (0)

#define AV_STEP(T, XC, XN, RP)                                                     \
    do {                                                                           \
        short8 hf[4];                                                              \
        _Pragma("unroll") for (int kt = 0; kt < 4; ++kt) {                         \
            int byt = (RP) * 4096 + np * 256 + kt * 64 + k8 * 16;                  \
            hf[kt] = *(const short8*)(hbase + (byt ^ ((np & 7) << 4)));            \
        }                                                                          \
        f32x4 acc[4];                                                              \
        _Pragma("unroll") for (int g = 0; g < 4; ++g) acc[g] = (f32x4)(0.f);       \
        _Pragma("unroll") for (int kt = 0; kt < 4; ++kt)                           \
            _Pragma("unroll") for (int g = 0; g < 4; ++g)                          \
                acc[g] = __builtin_amdgcn_mfma_f32_16x16x32_bf16(wres[kt][g], hf[kt], acc[g], 0, 0, 0); \
        { const ushort* xrn = xbase + (size_t)(((T) + 1) & 127) * 8192;            \
          _Pragma("unroll") for (int g = 0; g < 4; ++g)                            \
              (XN)[g] = *(const uint2*)(xrn + g * 256); }                          \
        _Pragma("unroll") for (int g = 0; g < 4; ++g) {                            \
            acc[g][0] += bf2f((ushort)((XC)[g].x & 0xffffu));                      \
            acc[g][1] += bf2f((ushort)((XC)[g].x >> 16));                          \
            acc[g][2] += bf2f((ushort)((XC)[g].y & 0xffffu));                      \
            acc[g][3] += bf2f((ushort)((XC)[g].y >> 16));                          \
        }                                                                          \
        ushort hq[4];                                                              \
        _Pragma("unroll") for (int q = 0; q < 4; ++q) {                            \
            float cc = sigm(acc[1][q]) * c_st0[q] + sigm(acc[0][q]) * tanh_(acc[2][q]); \
            c_st0[q] = cc;                                                         \
            hq[q] = f2bf(sigm(acc[3][q]) * tanh_(cc));                             \
        }                                                                          \
        uint2 hw;                                                                  \
        hw.x = (uint)hq[0] | ((uint)hq[1] << 16);                                  \
        hw.y = (uint)hq[2] | ((uint)hq[3] << 16);                                  \
        {                                                                          \
            int byt = ((RP) ^ 1) * 4096 + np * 256 + w * 32 + k8 * 8;              \
            *(uint2*)(hbase + (byt ^ ((np & 7) << 4))) = hw;                       \
            *(uint2*)(zb + zrow + (size_t)(T) * 512) = hw;                         \
        }                                                                          \
        BARRIER_LIGHT();                                                           \
    } while (0)

__global__ __launch_bounds__(512) void lstm_mfma5(
    const ushort* __restrict__ xpt, const ushort* __restrict__ xpa,
    const ushort* __restrict__ xpv, const ushort* __restrict__ WFt,
    const ushort* __restrict__ WFa, const ushort* __restrict__ WFv,
    ushort* __restrict__ zb)
{
    __shared__ __align__(16) char smem[147456];   // 16KB h + 8 waves x 16KB W
    const int tid  = threadIdx.x;
    const int lane = tid & 63;
    const int w    = tid >> 6;
    const int np   = lane & 15;      // batch column
    const int k8   = lane >> 4;      // k-chunk / row-quad
    const int bid  = blockIdx.x;
    char* hbase = smem;
    char* wbuf  = smem + 16384 + w * 16384;

    if (bid < 16) {
        // ------------------------- text: H=256, K=256 -------------------------
        const int bt = bid;
        const ushort* xbase = xpt + (size_t)bt * 2097152 + w * 2048 + np * 16 + k8 * 4;
        const size_t  zrow  = ((size_t)(bt * 16 + np) * 128) * 512 + 256 + w * 32 + k8 * 4;

        STAGE_W(0);
        STAGE_W(1);
        uint2 xvA[8], xvB[8];
#pragma unroll
        for (int e = 0; e < 8; ++e) xvA[e] = *(const uint2*)(xbase + e * 256);

        for (int i = tid; i < 4096; i += 512) ((uint*)hbase)[i] = 0u;
        float c_st[2][4];
#pragma unroll
        for (int s = 0; s < 2; ++s)
#pragma unroll
            for (int q = 0; q < 4; ++q) c_st[s][q] = 0.f;
        __syncthreads();   // drains everything; vmcnt counting restarts clean

#pragma unroll 1
        for (int t = 0; t < 128; t += 2) {
            TEXT_STEP(t,     xvA, xvB, 0);
            TEXT_STEP(t + 1, xvB, xvA, 1);
        }
    } else {
        // ----------------------- audio / video: H=128, K=128 -------------------
        const bool isA = bid < 32;
        const int bt = bid - (isA ? 16 : 32);
        const ushort* xp = isA ? xpa : xpv;
        const ushort* WF = isA ? WFa : WFv;
        const int zoff = isA ? 0 : 128;

        short8 wres[4][4];
#pragma unroll
        for (int kt = 0; kt < 4; ++kt)
#pragma unroll
            for (int g = 0; g < 4; ++g)
                wres[kt][g] = *(const short8*)(WF + (size_t)((kt * 8 + w) * 4 + g) * 512 + np * 32 + k8 * 8);
        for (int i = tid; i < 2048; i += 512) ((uint*)hbase)[i] = 0u;
        float c_st0[4];
#pragma unroll
        for (int q = 0; q < 4; ++q) c_st0[q] = 0.f;
        __syncthreads();

        const ushort* xbase = xp + (size_t)bt * 1048576 + w * 1024 + np * 16 + k8 * 4;
        const size_t  zrow  = ((size_t)(bt * 16 + np) * 128) * 512 + zoff + w * 16 + k8 * 4;

        uint2 xvA[4], xvB[4];
#pragma unroll
        for (int g = 0; g < 4; ++g) xvA[g] = *(const uint2*)(xbase + g * 256);

#pragma unroll 1
        for (int t = 0; t < 128; t += 2) {
            AV_STEP(t,     xvA, xvB, 0);
            AV_STEP(t + 1, xvB, xvA, 1);
        }
    }
}

// ---------------------------------------------------------------------------
// MFMA fusion head (verified R2-R14).
// ---------------------------------------------------------------------------
__global__ __launch_bounds__(256) void fuse_mfma(
    const ushort* __restrict__ zb, const ushort* __restrict__ W1b,
    const ushort* __restrict__ W2ab, const ushort* __restrict__ W2bb,
    const float* __restrict__ b1, const float* __restrict__ b2,
    const float* __restrict__ W2, float* __restrict__ zf)
{
    constexpr int STR = 40;
    __shared__ ushort As[64 * STR];
    __shared__ ushort W1s[256 * STR];
    __shared__ ushort W2s[256 * STR];

    const int tid  = threadIdx.x;
    const int lane = tid & 63;
    const int wave = tid >> 6;
    const int b    = blockIdx.y;
    const int r0   = blockIdx.x * 256;
    const int n0w  = wave * 64;

    const int a_row  = tid >> 2;
    const int a_c8   = (tid & 3) * 8;
    const int fr_row = lane & 15;
    const int fr_k   = (lane >> 4) * 8;

    f32x4 acc1[4][4], acc2[4][4];
#pragma unroll
    for (int i = 0; i < 4; ++i)
#pragma unroll
        for (int j = 0; j < 4; ++j) {
            acc1[i][j] = (f32x4)(0.f);
            acc2[i][j] = (f32x4)(0.f);
        }

    for (int pass = 0; pass < 2; ++pass) {
        const ushort* wsrc = pass ? W2bb : W2ab;
        for (int c0 = 0; c0 < 512; c0 += 32) {
            {
                const int4 v = *(const int4*)(zb +
                    (((size_t)b * 128 + 2 * a_row + pass) * 512 + c0 + a_c8));
                *(int4*)&As[a_row * STR + a_c8] = v;
            }
            if (pass == 0) {
                const ushort* w1p = W1b + (size_t)(r0 + tid) * 512 + c0;
#pragma unroll
                for (int j = 0; j < 4; ++j)
                    *(int4*)&W1s[tid * STR + j * 8] = *(const int4*)(w1p + j * 8);
            }
            {
                const ushort* w2p = wsrc + (size_t)(r0 + tid) * 512 + c0;
#pragma unroll
                for (int j = 0; j < 4; ++j)
                    *(int4*)&W2s[tid * STR + j * 8] = *(const int4*)(w2p + j * 8);
            }
            __syncthreads();

            short8 af[4], w2f[4];
#pragma unroll
            for (int mi = 0; mi < 4; ++mi)
                af[mi] = *(const short8*)&As[(mi * 16 + fr_row) * STR + fr_k];
#pragma unroll
            for (int ni = 0; ni < 4; ++ni)
                w2f[ni] = *(const short8*)&W2s[(n0w + ni * 16 + fr_row) * STR + fr_k];

            if (pass == 0) {
                short8 w1f[4];
#pragma unroll
                for (int ni = 0; ni < 4; ++ni)
                    w1f[ni] = *(const short8*)&W1s[(n0w + ni * 16 + fr_row) * STR + fr_k];
#pragma unroll
                for (int mi = 0; mi < 4; ++mi)
#pragma unroll
                    for (int ni = 0; ni < 4; ++ni) {
                        acc1[mi][ni] = __builtin_amdgcn_mfma_f32_16x16x32_bf16(
                            af[mi], w1f[ni], acc1[mi][ni], 0, 0, 0);
                        acc2[mi][ni] = __builtin_amdgcn_mfma_f32_16x16x32_bf16(
                            af[mi], w2f[ni], acc2[mi][ni], 0, 0, 0);
                    }
            } else {
#pragma unroll
                for (int mi = 0; mi < 4; ++mi)
#pragma unroll
                    for (int ni = 0; ni < 4; ++ni)
                        acc2[mi][ni] = __builtin_amdgcn_mfma_f32_16x16x32_bf16(
                            af[mi], w2f[ni], acc2[mi][ni], 0, 0, 0);
            }
            __syncthreads();
        }
    }

#pragma unroll
    for (int ni = 0; ni < 4; ++ni) {
        const int r = r0 + n0w + ni * 16 + fr_row;
        const float bb1 = b1[r];
        const float bb2 = b2[r] + W2[(size_t)r * 1025];
        float s = 0.f;
#pragma unroll
        for (int mi = 0; mi < 4; ++mi)
#pragma unroll
            for (int q = 0; q < 4; ++q)
                s += (acc1[mi][ni][q] + bb1) * (acc2[mi][ni][q] + bb2);
        s += __shfl_xor(s, 16);
        s += __shfl_xor(s, 32);
        if ((lane >> 4) == 0)
            zf[(size_t)b * 2048 + r] = s * (1.0f / 64.0f);
    }
}

__global__ void final_out(const float* __restrict__ zf, const float* __restrict__ fw,
                          float* __restrict__ out)
{
    int idx = blockIdx.x * 256 + threadIdx.x;
    int b = idx >> 4, o = idx & 15;
    float s = 0.f;
#pragma unroll
    for (int r = 0; r < 128; ++r)
        s = fmaf(fw[r], zf[(size_t)b * 2048 + r * 16 + o], s);
    out[idx] = s;
}

extern "C" void kernel_launch(void* const* d_in, const int* in_sizes, int n_in,
                              void* d_out, int out_size, void* d_ws, size_t ws_size,
                              hipStream_t stream)
{
    const float* text_x  = (const float*)d_in[0];
    const float* audio_x = (const float*)d_in[1];
    const float* video_x = (const float*)d_in[2];
    const float* W_ih_t  = (const float*)d_in[3];
    const float* W_hh_t  = (const float*)d_in[4];
    const float* b_t     = (const float*)d_in[5];
    const float* W_ih_a  = (const float*)d_in[6];
    const float* W_hh_a  = (const float*)d_in[7];
    const float* b_a     = (const float*)d_in[8];
    const float* W_ih_v  = (const float*)d_in[9];
    const float* W_hh_v  = (const float*)d_in[10];
    const float* b_v     = (const float*)d_in[11];
    const float* W1      = (const float*)d_in[12];
    const float* b1      = (const float*)d_in[13];
    const float* W2      = (const float*)d_in[14];
    const float* b2      = (const float*)d_in[15];
    const float* fw      = (const float*)d_in[16];
    float* out = (float*)d_out;

    // workspace layout (bytes)
    char* base = (char*)d_ws;
    ushort* xpt  = (ushort*)(base);                 // 67108864
    ushort* xpa  = (ushort*)(base + 67108864);      // 33554432
    ushort* xpv  = (ushort*)(base + 100663296);     // 33554432
    ushort* zbuf = (ushort*)(base + 134217728);     // 33554432
    ushort* WFt  = (ushort*)(base + 167772160);     //   524288
    ushort* WFa  = (ushort*)(base + 168296448);     //   131072
    ushort* WFv  = (ushort*)(base + 168427520);     //   131072
    ushort* W1b  = (ushort*)(base + 168558592);     //  2097152
    ushort* W2ab = (ushort*)(base + 170655744);     //  2097152
    ushort* W2bb = (ushort*)(base + 172752896);     //  2097152
    float*  zf   = (float*)(base + 174850048);      //  2097152
    ushort* txb  = (ushort*)(base + 176947200);     // 50331648
    ushort* axb  = (ushort*)(base + 227278848);     //  4849664
    ushort* vxb  = (ushort*)(base + 232128512);     //  2293760
    ushort* wtb  = (ushort*)(base + 234422272);     //  1572864
    ushort* wab  = (ushort*)(base + 235995136);     //    75776
    ushort* wvb  = (ushort*)(base + 236070912);     //    35840

    cvt_all<<<14444, 256, 0, stream>>>(text_x, audio_x, video_x, W_ih_t, W_ih_a, W_ih_v,
                                       txb, axb, vxb, wtb, wab, wvb);

    gemm_mfma_b<<<dim3(8, 256), 256, 0, stream>>>(txb, wtb, b_t, xpt, 32768, 1024, 768);
    gemm_mfma_b<<<dim3(4, 256), 256, 0, stream>>>(axb, wab, b_a, xpa, 32768, 512, 74);
    gemm_mfma_b<<<dim3(4, 256), 256, 0, stream>>>(vxb, wvb, b_v, xpv, 32768, 512, 35);
    wfrag_pack<<<1536, 256, 0, stream>>>(W_hh_t, W_hh_a, W_hh_v, WFt, WFa, WFv);
    wf_pack<<<4096, 256, 0, stream>>>(W1, W2, W1b, W2ab, W2bb);
    lstm_mfma5<<<48, 512, 0, stream>>>(xpt, xpa, xpv, WFt, WFa, WFv, zbuf);
    fuse_mfma<<<dim3(8, 256), 256, 0, stream>>>(zbuf, W1b, W2ab, W2bb, b1, b2, W2, zf);
    final_out<<<16, 256, 0, stream>>>(zf, fw, out);
}